// Round 1
// baseline (5182.452 us; speedup 1.0000x reference)
//
#include <hip/hip_runtime.h>

// Problem dims
#define T_STEPS 1024
#define A_SETS 32
#define B_ITEMS 8
#define D_EMB 128
#define H1 512
#define H2 256
#define NCLS 100
#define G4H 2048   // 4*H1
#define X_DIM 256  // 2*D

// Workspace layout (float offsets)
#define OFF_X    0
#define OFF_GX   (OFF_X + T_STEPS * X_DIM)        // x: [1024,256]
#define OFF_HS   (OFF_GX + T_STEPS * G4H)         // gx: [1024,2048]
#define OFF_HBUF (OFF_HS + T_STEPS * H1)          // hs: [1024,512]
#define OFF_FLAG (OFF_HBUF + 2 * H1)              // hbuf: [2][512]
// flags: 16 ints

#define LSTM_G 16  // workgroups in recurrent kernel

__global__ void init_kernel(float* __restrict__ ws) {
    int tid = threadIdx.x;
    if (tid < 2 * H1) ws[OFF_HBUF + tid] = 0.f;   // h_0 = 0 (both buffers)
    if (tid < 64) ((int*)(ws + OFF_FLAG))[tid] = 0;
}

// One block per t. Threads 0-127: diag pool, 128-255: proc pool.
__global__ void pool_kernel(const int* __restrict__ diag, const int* __restrict__ proc,
                            const float* __restrict__ emb, float* __restrict__ ws) {
    __shared__ int sidx[2][A_SETS * B_ITEMS];
    int t = blockIdx.x;
    int tid = threadIdx.x;
    sidx[0][tid] = diag[t * 256 + tid];
    sidx[1][tid] = proc[t * 256 + tid];
    __syncthreads();
    int src = tid >> 7;
    int d = tid & 127;
    float acc = 0.f;
#pragma unroll 8
    for (int i = 0; i < 256; ++i) {
        acc += emb[(size_t)sidx[src][i] * D_EMB + d];
    }
    // mean over B (8) then sum over A == sum/8
    ws[OFF_X + t * X_DIM + src * D_EMB + d] = acc * 0.125f;
}

// gx = x @ W_ih^T + (b_ih + b_hh).  Grid (128, 8), 256 threads.
#define GX_TB 8
__global__ void gx_kernel(const float* __restrict__ W_ih, const float* __restrict__ b_ih,
                          const float* __restrict__ b_hh, float* __restrict__ ws) {
    __shared__ float xs[GX_TB][X_DIM];
    int tb = blockIdx.x;   // t-tile
    int jb = blockIdx.y;   // row-tile
    int tid = threadIdx.x;
    const float* x = ws + OFF_X;
    for (int i = tid; i < GX_TB * X_DIM; i += 256)
        xs[i >> 8][i & 255] = x[(size_t)(tb * GX_TB + (i >> 8)) * X_DIM + (i & 255)];
    __syncthreads();
    int row = jb * 256 + tid;
    float b = b_ih[row] + b_hh[row];
    float acc[GX_TB];
#pragma unroll
    for (int i = 0; i < GX_TB; ++i) acc[i] = b;
    const float4* wr = (const float4*)(W_ih + (size_t)row * X_DIM);
#pragma unroll 4
    for (int k4 = 0; k4 < X_DIM / 4; ++k4) {
        float4 w = wr[k4];
#pragma unroll
        for (int i = 0; i < GX_TB; ++i) {
            acc[i] = fmaf(w.x, xs[i][4 * k4 + 0], acc[i]);
            acc[i] = fmaf(w.y, xs[i][4 * k4 + 1], acc[i]);
            acc[i] = fmaf(w.z, xs[i][4 * k4 + 2], acc[i]);
            acc[i] = fmaf(w.w, xs[i][4 * k4 + 3], acc[i]);
        }
    }
    float* gx = ws + OFF_GX;
#pragma unroll
    for (int i = 0; i < GX_TB; ++i)
        gx[(size_t)(tb * GX_TB + i) * G4H + row] = acc[i];
}

// Persistent cooperative LSTM. 16 WGs x 512 threads. W_hh slice in VGPRs.
// Thread (r = tid>>2, p = tid&3): row r of this WG's 128 gate rows, segment p of the 512-dot.
// WG g owns hidden units [g*32, g*32+32).
__global__ void __launch_bounds__(512, 2)
lstm_kernel(const float* __restrict__ W_hh, float* __restrict__ ws) {
    __shared__ float h_lds[H1];
    __shared__ float gates[128];
    int g = blockIdx.x;
    int tid = threadIdx.x;
    int r = tid >> 2;
    int p = tid & 3;
    int gate = r >> 5;
    int jl = r & 31;
    int grow = gate * H1 + g * 32 + jl;   // global gate-row

    // Load this thread's 128 weights into registers.
    float w[128];
    const float4* wr = (const float4*)(W_hh + (size_t)grow * H1 + p * 128);
#pragma unroll
    for (int k = 0; k < 32; ++k) {
        float4 v = wr[k];
        w[4 * k + 0] = v.x; w[4 * k + 1] = v.y; w[4 * k + 2] = v.z; w[4 * k + 3] = v.w;
    }

    float* hbuf = ws + OFF_HBUF;
    int* flags = (int*)(ws + OFF_FLAG);
    float* hs = ws + OFF_HS;
    const float* gx = ws + OFF_GX;
    float c = 0.f;

    for (int s = 1; s <= T_STEPS; ++s) {
        int t = s - 1;
        // Wait until all WGs have published h_{s-1}.
        if (tid < 64) {
            int need = s - 1;
            while (true) {
                int v = (tid < LSTM_G)
                    ? __hip_atomic_load(&flags[tid], __ATOMIC_RELAXED, __HIP_MEMORY_SCOPE_AGENT)
                    : 0x7fffffff;
                if (__all(v >= need)) break;
                __builtin_amdgcn_s_sleep(1);
            }
        }
        __builtin_amdgcn_fence(__ATOMIC_ACQUIRE, "agent");
        __syncthreads();
        // Stage h_{s-1} into LDS (sc1 loads straight from L3).
        h_lds[tid] = __hip_atomic_load(&hbuf[((s - 1) & 1) * H1 + tid],
                                       __ATOMIC_RELAXED, __HIP_MEMORY_SCOPE_AGENT);
        __syncthreads();
        // Partial dot: 128 FMAs from registers.
        float acc = 0.f;
        const float4* h4 = (const float4*)(h_lds + p * 128);
#pragma unroll
        for (int k = 0; k < 32; ++k) {
            float4 hv = h4[k];
            acc = fmaf(w[4 * k + 0], hv.x, acc);
            acc = fmaf(w[4 * k + 1], hv.y, acc);
            acc = fmaf(w[4 * k + 2], hv.z, acc);
            acc = fmaf(w[4 * k + 3], hv.w, acc);
        }
        acc += __shfl_xor(acc, 1);
        acc += __shfl_xor(acc, 2);
        if (p == 0) gates[r] = acc + gx[(size_t)t * G4H + grow];
        __syncthreads();
        if (tid < 32) {
            float gi = gates[tid];
            float gf = gates[32 + tid];
            float gg = gates[64 + tid];
            float go = gates[96 + tid];
            gi = 1.f / (1.f + __expf(-gi));
            gf = 1.f / (1.f + __expf(-gf));
            go = 1.f / (1.f + __expf(-go));
            gg = tanhf(gg);
            c = gf * c + gi * gg;
            float h = go * tanhf(c);
            __hip_atomic_store(&hbuf[(s & 1) * H1 + g * 32 + tid], h,
                               __ATOMIC_RELAXED, __HIP_MEMORY_SCOPE_AGENT);
            hs[(size_t)t * H1 + g * 32 + tid] = h;  // for MLP kernel (kernel-boundary sync)
        }
        __syncthreads();  // ensures slice stores retired before flag release
        if (tid == 0)
            __hip_atomic_store(&flags[g], s, __ATOMIC_RELEASE, __HIP_MEMORY_SCOPE_AGENT);
    }
}

// h1 = relu(hs @ W1^T + b1); out = h1 @ W_out^T + b_out.  One block per t.
__global__ void mlp_kernel(const float* __restrict__ W1, const float* __restrict__ b1,
                           const float* __restrict__ W_out, const float* __restrict__ b_out,
                           const float* __restrict__ ws, float* __restrict__ out) {
    __shared__ float hsv[H1];
    __shared__ float h1v[H2];
    int t = blockIdx.x;
    int tid = threadIdx.x;  // 256
    const float* hs = ws + OFF_HS;
    hsv[tid] = hs[(size_t)t * H1 + tid];
    hsv[256 + tid] = hs[(size_t)t * H1 + 256 + tid];
    __syncthreads();
    float acc = b1[tid];
    const float4* wr = (const float4*)(W1 + (size_t)tid * H1);
#pragma unroll 4
    for (int k = 0; k < H1 / 4; ++k) {
        float4 w = wr[k];
        acc = fmaf(w.x, hsv[4 * k + 0], acc);
        acc = fmaf(w.y, hsv[4 * k + 1], acc);
        acc = fmaf(w.z, hsv[4 * k + 2], acc);
        acc = fmaf(w.w, hsv[4 * k + 3], acc);
    }
    h1v[tid] = fmaxf(acc, 0.f);
    __syncthreads();
    if (tid < NCLS) {
        float a2 = b_out[tid];
        const float4* w2 = (const float4*)(W_out + (size_t)tid * H2);
#pragma unroll 4
        for (int k = 0; k < H2 / 4; ++k) {
            float4 w = w2[k];
            a2 = fmaf(w.x, h1v[4 * k + 0], a2);
            a2 = fmaf(w.y, h1v[4 * k + 1], a2);
            a2 = fmaf(w.z, h1v[4 * k + 2], a2);
            a2 = fmaf(w.w, h1v[4 * k + 3], a2);
        }
        out[(size_t)t * NCLS + tid] = a2;
    }
}

extern "C" void kernel_launch(void* const* d_in, const int* in_sizes, int n_in,
                              void* d_out, int out_size, void* d_ws, size_t ws_size,
                              hipStream_t stream) {
    const int* diag = (const int*)d_in[0];
    const int* proc = (const int*)d_in[1];
    const float* emb = (const float*)d_in[2];
    const float* W_ih = (const float*)d_in[3];
    const float* W_hh = (const float*)d_in[4];
    const float* b_ih = (const float*)d_in[5];
    const float* b_hh = (const float*)d_in[6];
    const float* W1 = (const float*)d_in[7];
    const float* b1 = (const float*)d_in[8];
    const float* W_out = (const float*)d_in[9];
    const float* b_out = (const float*)d_in[10];
    float* ws = (float*)d_ws;
    float* out = (float*)d_out;

    hipLaunchKernelGGL(init_kernel, dim3(1), dim3(1024), 0, stream, ws);
    hipLaunchKernelGGL(pool_kernel, dim3(T_STEPS), dim3(256), 0, stream, diag, proc, emb, ws);
    hipLaunchKernelGGL(gx_kernel, dim3(T_STEPS / GX_TB, G4H / 256), dim3(256), 0, stream,
                       W_ih, b_ih, b_hh, ws);
    hipLaunchKernelGGL(lstm_kernel, dim3(LSTM_G), dim3(512), 0, stream, W_hh, ws);
    hipLaunchKernelGGL(mlp_kernel, dim3(T_STEPS), dim3(256), 0, stream,
                       W1, b1, W_out, b_out, ws, out);
}

// Round 2
// 2869.787 us; speedup vs baseline: 1.8059x; 1.8059x over previous
//
#include <hip/hip_runtime.h>

// Problem dims
#define T_STEPS 1024
#define A_SETS 32
#define B_ITEMS 8
#define D_EMB 128
#define H1 512
#define H2 256
#define NCLS 100
#define G4H 2048   // 4*H1
#define X_DIM 256  // 2*D

// Workspace layout (float offsets)
#define OFF_X    0
#define OFF_GX   (OFF_X + T_STEPS * X_DIM)        // x: [1024,256]
#define OFF_HS   (OFF_GX + T_STEPS * G4H)         // gx: [1024,2048]
#define OFF_SLOT (OFF_HS + T_STEPS * H1)          // slots: [2][512] u64 (packed tag|h)
// total floats = OFF_SLOT + 2048

#define LSTM_G 16  // workgroups in recurrent kernel

__global__ void init_kernel(float* __restrict__ ws) {
    int tid = threadIdx.x;  // 1024
    // zero both slot buffers: tag=0, h=0.0 (h_0 = 0). Poison would fake tags.
    ws[OFF_SLOT + tid] = 0.f;
    ws[OFF_SLOT + 1024 + tid] = 0.f;
}

// One block per t. Threads 0-127: diag pool, 128-255: proc pool.
__global__ void pool_kernel(const int* __restrict__ diag, const int* __restrict__ proc,
                            const float* __restrict__ emb, float* __restrict__ ws) {
    __shared__ int sidx[2][A_SETS * B_ITEMS];
    int t = blockIdx.x;
    int tid = threadIdx.x;
    sidx[0][tid] = diag[t * 256 + tid];
    sidx[1][tid] = proc[t * 256 + tid];
    __syncthreads();
    int src = tid >> 7;
    int d = tid & 127;
    float acc = 0.f;
#pragma unroll 8
    for (int i = 0; i < 256; ++i) {
        acc += emb[(size_t)sidx[src][i] * D_EMB + d];
    }
    // mean over B (8) then sum over A == sum/8
    ws[OFF_X + t * X_DIM + src * D_EMB + d] = acc * 0.125f;
}

// gx = x @ W_ih^T + (b_ih + b_hh).  Grid (128, 8), 256 threads.
#define GX_TB 8
__global__ void gx_kernel(const float* __restrict__ W_ih, const float* __restrict__ b_ih,
                          const float* __restrict__ b_hh, float* __restrict__ ws) {
    __shared__ float xs[GX_TB][X_DIM];
    int tb = blockIdx.x;   // t-tile
    int jb = blockIdx.y;   // row-tile
    int tid = threadIdx.x;
    const float* x = ws + OFF_X;
    for (int i = tid; i < GX_TB * X_DIM; i += 256)
        xs[i >> 8][i & 255] = x[(size_t)(tb * GX_TB + (i >> 8)) * X_DIM + (i & 255)];
    __syncthreads();
    int row = jb * 256 + tid;
    float b = b_ih[row] + b_hh[row];
    float acc[GX_TB];
#pragma unroll
    for (int i = 0; i < GX_TB; ++i) acc[i] = b;
    const float4* wr = (const float4*)(W_ih + (size_t)row * X_DIM);
#pragma unroll 4
    for (int k4 = 0; k4 < X_DIM / 4; ++k4) {
        float4 w = wr[k4];
#pragma unroll
        for (int i = 0; i < GX_TB; ++i) {
            acc[i] = fmaf(w.x, xs[i][4 * k4 + 0], acc[i]);
            acc[i] = fmaf(w.y, xs[i][4 * k4 + 1], acc[i]);
            acc[i] = fmaf(w.z, xs[i][4 * k4 + 2], acc[i]);
            acc[i] = fmaf(w.w, xs[i][4 * k4 + 3], acc[i]);
        }
    }
    float* gx = ws + OFF_GX;
#pragma unroll
    for (int i = 0; i < GX_TB; ++i)
        gx[(size_t)(tb * GX_TB + i) * G4H + row] = acc[i];
}

// Persistent cooperative LSTM. 16 WGs x 512 threads. W_hh slice in VGPRs.
// Lane mapping: tid = j*16 + seg*4 + gate   (j: hidden unit within WG's 32,
// seg: 128-wide segment of the 512-dot, gate: i/f/g/o).
// h exchange: packed 64-bit (tag<<32 | h_bits) relaxed agent atomics,
// double-buffered by step parity. No fences needed: the data rides in the
// same atomic word as the tag, and double-buffering guarantees a poller at
// step s can only ever see tag s-1 (never s+1) in its buffer.
__global__ void __launch_bounds__(512, 1)
lstm_kernel(const float* __restrict__ W_hh, float* __restrict__ ws) {
    __shared__ float h_pad[2][4 * 136];   // double-buffered, padded: conflict-free b128 reads
    const int g = blockIdx.x;
    const int tid = threadIdx.x;
    const int lane = tid & 63;
    const int j = tid >> 4;
    const int seg = (tid >> 2) & 3;
    const int gate = tid & 3;
    const int unit = g * 32 + j;
    const int grow = gate * H1 + unit;

    // 128 weights of row `grow`, segment `seg`, in registers.
    float w[128];
    {
        const float4* wr = (const float4*)(W_hh + (size_t)grow * H1 + seg * 128);
#pragma unroll
        for (int k = 0; k < 32; ++k) {
            float4 v = wr[k];
            w[4 * k + 0] = v.x; w[4 * k + 1] = v.y;
            w[4 * k + 2] = v.z; w[4 * k + 3] = v.w;
        }
    }

    unsigned long long* slots = (unsigned long long*)(ws + OFF_SLOT);
    float* hs = ws + OFF_HS;
    const float* gx = ws + OFF_GX;
    const int stage_row = tid >> 7;
    const int stage_col = tid & 127;
    const bool comb = ((tid & 15) == 0);
    const int base = lane & 48;
    float c = 0.f;

    for (int s = 1; s <= T_STEPS; ++s) {
        const int t = s - 1;
        // Prefetch gx for this step (independent of polled data).
        float gxv = gx[(size_t)t * G4H + grow];
        // Poll own slot in buffer (s-1)&1 until tag >= s-1; value rides along.
        const unsigned need = (unsigned)(s - 1);
        unsigned long long v;
        do {
            v = __hip_atomic_load(&slots[((s - 1) & 1) * H1 + tid],
                                  __ATOMIC_RELAXED, __HIP_MEMORY_SCOPE_AGENT);
        } while ((unsigned)(v >> 32) < need);
        float* hp = h_pad[s & 1];
        hp[stage_row * 136 + stage_col] = __uint_as_float((unsigned)v);
        __syncthreads();
        // Partial dot: 128 FMAs from registers; LDS reads broadcast within seg,
        // conflict-free across seg (136-float stride => 8-bank offset).
        float acc = 0.f;
        const float4* h4 = (const float4*)(hp + seg * 136);
#pragma unroll
        for (int k = 0; k < 32; ++k) {
            float4 hv = h4[k];
            acc = fmaf(w[4 * k + 0], hv.x, acc);
            acc = fmaf(w[4 * k + 1], hv.y, acc);
            acc = fmaf(w[4 * k + 2], hv.z, acc);
            acc = fmaf(w[4 * k + 3], hv.w, acc);
        }
        acc += __shfl_xor(acc, 4);   // reduce over seg (bits 2-3 of lane)
        acc += __shfl_xor(acc, 8);
        acc += gxv;
        // Gather the 4 gates of this j-group (lanes base+0..3 hold seg=0 copies).
        float gi = __shfl(acc, base + 0);
        float gf = __shfl(acc, base + 1);
        float gg = __shfl(acc, base + 2);
        float go = __shfl(acc, base + 3);
        if (comb) {
            gi = 1.f / (1.f + __expf(-gi));
            gf = 1.f / (1.f + __expf(-gf));
            go = 1.f / (1.f + __expf(-go));
            gg = tanhf(gg);
            c = fmaf(gf, c, gi * gg);
            float h = go * tanhf(c);
            unsigned long long pv =
                ((unsigned long long)(unsigned)s << 32) | (unsigned long long)__float_as_uint(h);
            __hip_atomic_store(&slots[(s & 1) * H1 + unit], pv,
                               __ATOMIC_RELAXED, __HIP_MEMORY_SCOPE_AGENT);
            hs[(size_t)t * H1 + unit] = h;   // consumed by mlp_kernel (kernel-boundary sync)
        }
        // No trailing barrier: LDS is double-buffered, and the slot protocol
        // prevents any thread from getting 2 steps ahead of a reader.
    }
}

// h1 = relu(hs @ W1^T + b1); out = h1 @ W_out^T + b_out.  One block per t.
__global__ void mlp_kernel(const float* __restrict__ W1, const float* __restrict__ b1,
                           const float* __restrict__ W_out, const float* __restrict__ b_out,
                           const float* __restrict__ ws, float* __restrict__ out) {
    __shared__ float hsv[H1];
    __shared__ float h1v[H2];
    int t = blockIdx.x;
    int tid = threadIdx.x;  // 256
    const float* hs = ws + OFF_HS;
    hsv[tid] = hs[(size_t)t * H1 + tid];
    hsv[256 + tid] = hs[(size_t)t * H1 + 256 + tid];
    __syncthreads();
    float acc = b1[tid];
    const float4* wr = (const float4*)(W1 + (size_t)tid * H1);
#pragma unroll 4
    for (int k = 0; k < H1 / 4; ++k) {
        float4 w = wr[k];
        acc = fmaf(w.x, hsv[4 * k + 0], acc);
        acc = fmaf(w.y, hsv[4 * k + 1], acc);
        acc = fmaf(w.z, hsv[4 * k + 2], acc);
        acc = fmaf(w.w, hsv[4 * k + 3], acc);
    }
    h1v[tid] = fmaxf(acc, 0.f);
    __syncthreads();
    if (tid < NCLS) {
        float a2 = b_out[tid];
        const float4* w2 = (const float4*)(W_out + (size_t)tid * H2);
#pragma unroll 4
        for (int k = 0; k < H2 / 4; ++k) {
            float4 w = w2[k];
            a2 = fmaf(w.x, h1v[4 * k + 0], a2);
            a2 = fmaf(w.y, h1v[4 * k + 1], a2);
            a2 = fmaf(w.z, h1v[4 * k + 2], a2);
            a2 = fmaf(w.w, h1v[4 * k + 3], a2);
        }
        out[(size_t)t * NCLS + tid] = a2;
    }
}

extern "C" void kernel_launch(void* const* d_in, const int* in_sizes, int n_in,
                              void* d_out, int out_size, void* d_ws, size_t ws_size,
                              hipStream_t stream) {
    const int* diag = (const int*)d_in[0];
    const int* proc = (const int*)d_in[1];
    const float* emb = (const float*)d_in[2];
    const float* W_ih = (const float*)d_in[3];
    const float* W_hh = (const float*)d_in[4];
    const float* b_ih = (const float*)d_in[5];
    const float* b_hh = (const float*)d_in[6];
    const float* W1 = (const float*)d_in[7];
    const float* b1 = (const float*)d_in[8];
    const float* W_out = (const float*)d_in[9];
    const float* b_out = (const float*)d_in[10];
    float* ws = (float*)d_ws;
    float* out = (float*)d_out;

    hipLaunchKernelGGL(init_kernel, dim3(1), dim3(1024), 0, stream, ws);
    hipLaunchKernelGGL(pool_kernel, dim3(T_STEPS), dim3(256), 0, stream, diag, proc, emb, ws);
    hipLaunchKernelGGL(gx_kernel, dim3(T_STEPS / GX_TB, G4H / 256), dim3(256), 0, stream,
                       W_ih, b_ih, b_hh, ws);
    hipLaunchKernelGGL(lstm_kernel, dim3(LSTM_G), dim3(512), 0, stream, W_hh, ws);
    hipLaunchKernelGGL(mlp_kernel, dim3(T_STEPS), dim3(256), 0, stream,
                       W1, b1, W_out, b_out, ws, out);
}

// Round 4
// 2698.935 us; speedup vs baseline: 1.9202x; 1.0633x over previous
//
#include <hip/hip_runtime.h>

// Problem dims
#define T_STEPS 1024
#define A_SETS 32
#define B_ITEMS 8
#define D_EMB 128
#define H1 512
#define H2 256
#define NCLS 100
#define G4H 2048   // 4*H1
#define X_DIM 256  // 2*D

// Workspace layout (float offsets)
#define OFF_X    0
#define OFF_GX   (OFF_X + T_STEPS * X_DIM)        // x: [1024,256]
#define OFF_HS   (OFF_GX + T_STEPS * G4H)         // gx: [1024,2048]
#define OFF_SLOT (OFF_HS + T_STEPS * H1)          // slots: [2][512] u64 (packed tag|h)

#define LSTM_G 32  // workgroups in recurrent kernel (16 units each)

__device__ __forceinline__ float fast_rcp(float d) {
    float r = __builtin_amdgcn_rcpf(d);
    return r * (2.f - d * r);   // one Newton step: ~0.5 ulp
}
__device__ __forceinline__ float fast_sigmoid(float x) {
    return fast_rcp(1.f + __expf(-x));
}
__device__ __forceinline__ float fast_tanh(float x) {
    // tanh(x) = 1 - 2/(1+e^{2x}); exact at +-inf, ~1e-7 rel err
    return 1.f - 2.f * fast_rcp(1.f + __expf(2.f * x));
}

__global__ void init_kernel(float* __restrict__ ws) {
    int tid = threadIdx.x;  // 1024
    // zero both slot buffers: tag=0, h=0.0 (h_0 = 0). Poison would fake tags.
    ws[OFF_SLOT + tid] = 0.f;
    ws[OFF_SLOT + 1024 + tid] = 0.f;
}

// One block per t. Threads 0-127: diag pool, 128-255: proc pool.
__global__ void pool_kernel(const int* __restrict__ diag, const int* __restrict__ proc,
                            const float* __restrict__ emb, float* __restrict__ ws) {
    __shared__ int sidx[2][A_SETS * B_ITEMS];
    int t = blockIdx.x;
    int tid = threadIdx.x;
    sidx[0][tid] = diag[t * 256 + tid];
    sidx[1][tid] = proc[t * 256 + tid];
    __syncthreads();
    int src = tid >> 7;
    int d = tid & 127;
    float acc = 0.f;
#pragma unroll 8
    for (int i = 0; i < 256; ++i) {
        acc += emb[(size_t)sidx[src][i] * D_EMB + d];
    }
    ws[OFF_X + t * X_DIM + src * D_EMB + d] = acc * 0.125f;  // mean over B, sum over A
}

// gx = x @ W_ih^T + (b_ih + b_hh).  Grid (128, 8), 256 threads.
#define GX_TB 8
__global__ void gx_kernel(const float* __restrict__ W_ih, const float* __restrict__ b_ih,
                          const float* __restrict__ b_hh, float* __restrict__ ws) {
    __shared__ float xs[GX_TB][X_DIM];
    int tb = blockIdx.x;   // t-tile
    int jb = blockIdx.y;   // row-tile
    int tid = threadIdx.x;
    const float* x = ws + OFF_X;
    for (int i = tid; i < GX_TB * X_DIM; i += 256)
        xs[i >> 8][i & 255] = x[(size_t)(tb * GX_TB + (i >> 8)) * X_DIM + (i & 255)];
    __syncthreads();
    int row = jb * 256 + tid;
    float b = b_ih[row] + b_hh[row];
    float acc[GX_TB];
#pragma unroll
    for (int i = 0; i < GX_TB; ++i) acc[i] = b;
    const float4* wr = (const float4*)(W_ih + (size_t)row * X_DIM);
#pragma unroll 4
    for (int k4 = 0; k4 < X_DIM / 4; ++k4) {
        float4 w = wr[k4];
#pragma unroll
        for (int i = 0; i < GX_TB; ++i) {
            acc[i] = fmaf(w.x, xs[i][4 * k4 + 0], acc[i]);
            acc[i] = fmaf(w.y, xs[i][4 * k4 + 1], acc[i]);
            acc[i] = fmaf(w.z, xs[i][4 * k4 + 2], acc[i]);
            acc[i] = fmaf(w.w, xs[i][4 * k4 + 3], acc[i]);
        }
    }
    float* gx = ws + OFF_GX;
#pragma unroll
    for (int i = 0; i < GX_TB; ++i)
        gx[(size_t)(tb * GX_TB + i) * G4H + row] = acc[i];
}

// Persistent cooperative LSTM. 32 WGs x 512 threads; each WG owns 16 hidden units.
// Lane mapping: tid = j*32 + seg*4 + gate  (j: unit within WG [0,16), seg: 64-wide
// segment of the 512-dot [0,8), gate: i/f/g/o). Each thread holds 64 weights in
// float4 regs (statically indexed -> VGPRs).
// h exchange: packed 64-bit (tag<<32 | h_bits) relaxed agent atomics, double-
// buffered by step parity. Safety: a producer reaches step s+1 only after ALL
// slots carry tag s, which requires every WG to have passed its step-s barrier,
// which requires every thread to have finished reading step s-1 -- so the
// buffer being overwritten (parity (s+1)&1 == (s-1)&1) has no pending readers.
__global__ void __launch_bounds__(512, 2)
lstm_kernel(const float* __restrict__ W_hh, float* __restrict__ ws) {
    __shared__ float h_pad[2][8 * 68];   // 8 segments, stride 68: b128 reads hit
                                         // banks {0,4,...,28} -- conflict-free
    const int g = blockIdx.x;
    const int tid = threadIdx.x;
    const int lane = tid & 63;
    const int j = tid >> 5;          // unit within WG
    const int seg = (tid >> 2) & 7;  // 64-float segment
    const int gate = tid & 3;
    const int unit = g * 16 + j;
    const int grow = gate * H1 + unit;

    // 64 weights of row `grow`, segment `seg`, in registers.
    float4 w4[16];
    {
        const float4* wr = (const float4*)(W_hh + (size_t)grow * H1 + seg * 64);
#pragma unroll
        for (int k = 0; k < 16; ++k) w4[k] = wr[k];
    }

    unsigned long long* slots = (unsigned long long*)(ws + OFF_SLOT);
    float* hs = ws + OFF_HS;
    const float* gx = ws + OFF_GX;
    const int stage_off = (tid >> 6) * 68 + (tid & 63);
    const bool comb = ((tid & 31) == 0);
    const int base = lane & 32;
    float c = 0.f;

    for (int s = 1; s <= T_STEPS; ++s) {
        const int t = s - 1;
        float gxv = gx[(size_t)t * G4H + grow];   // prefetch (L2/L3 resident)
        // Poll own slot in buffer (s-1)&1 until tag >= s-1; value rides along.
        const unsigned need = (unsigned)(s - 1);
        unsigned long long v;
        do {
            v = __hip_atomic_load(&slots[((s - 1) & 1) * H1 + tid],
                                  __ATOMIC_RELAXED, __HIP_MEMORY_SCOPE_AGENT);
        } while ((unsigned)(v >> 32) < need);
        float* hp = h_pad[s & 1];
        hp[stage_off] = __uint_as_float((unsigned)v);
        __syncthreads();
        // Partial dot: 64 FMAs from registers.
        float acc = 0.f;
        const float4* h4 = (const float4*)(hp + seg * 68);
#pragma unroll
        for (int k = 0; k < 16; ++k) {
            float4 hv = h4[k];
            acc = fmaf(w4[k].x, hv.x, acc);
            acc = fmaf(w4[k].y, hv.y, acc);
            acc = fmaf(w4[k].z, hv.z, acc);
            acc = fmaf(w4[k].w, hv.w, acc);
        }
        acc += __shfl_xor(acc, 4);    // reduce over seg (lane bits 2-4)
        acc += __shfl_xor(acc, 8);
        acc += __shfl_xor(acc, 16);
        acc += gxv;
        // Gates of this unit sit at lanes base+0..3 (seg==0 lanes).
        float gi = __shfl(acc, base + 0);
        float gf = __shfl(acc, base + 1);
        float gg = __shfl(acc, base + 2);
        float go = __shfl(acc, base + 3);
        if (comb) {
            gi = fast_sigmoid(gi);
            gf = fast_sigmoid(gf);
            go = fast_sigmoid(go);
            gg = fast_tanh(gg);
            c = fmaf(gf, c, gi * gg);
            float h = go * fast_tanh(c);
            unsigned long long pv =
                ((unsigned long long)(unsigned)s << 32) | (unsigned long long)__float_as_uint(h);
            __hip_atomic_store(&slots[(s & 1) * H1 + unit], pv,
                               __ATOMIC_RELAXED, __HIP_MEMORY_SCOPE_AGENT);
            hs[(size_t)t * H1 + unit] = h;   // consumed by mlp_kernel
        }
        // No trailing barrier needed (see header comment).
    }
}

// h1 = relu(hs @ W1^T + b1); out = h1 @ W_out^T + b_out.
// Tiled: 8 timesteps per block -> 8x weight reuse. Grid 128, 256 threads.
#define MLP_TB 8
__global__ void mlp_kernel(const float* __restrict__ W1, const float* __restrict__ b1,
                           const float* __restrict__ W_out, const float* __restrict__ b_out,
                           const float* __restrict__ ws, float* __restrict__ out) {
    __shared__ float hsv[MLP_TB][H1];   // 16 KB
    __shared__ float h1v[MLP_TB][H2];   // 8 KB
    int t0 = blockIdx.x * MLP_TB;
    int tid = threadIdx.x;  // 256
    const float* hs = ws + OFF_HS;
    for (int i = tid; i < MLP_TB * H1; i += 256)
        hsv[i >> 9][i & 511] = hs[(size_t)t0 * H1 + i];
    __syncthreads();
    float b = b1[tid];
    float acc[MLP_TB];
#pragma unroll
    for (int i = 0; i < MLP_TB; ++i) acc[i] = b;
    const float4* wr = (const float4*)(W1 + (size_t)tid * H1);
#pragma unroll 4
    for (int k = 0; k < H1 / 4; ++k) {
        float4 w = wr[k];
#pragma unroll
        for (int i = 0; i < MLP_TB; ++i) {
            acc[i] = fmaf(w.x, hsv[i][4 * k + 0], acc[i]);
            acc[i] = fmaf(w.y, hsv[i][4 * k + 1], acc[i]);
            acc[i] = fmaf(w.z, hsv[i][4 * k + 2], acc[i]);
            acc[i] = fmaf(w.w, hsv[i][4 * k + 3], acc[i]);
        }
    }
#pragma unroll
    for (int i = 0; i < MLP_TB; ++i) h1v[i][tid] = fmaxf(acc[i], 0.f);
    __syncthreads();
    if (tid < NCLS) {
        const float4* w2 = (const float4*)(W_out + (size_t)tid * H2);
        float b2 = b_out[tid];
#pragma unroll
        for (int i = 0; i < MLP_TB; ++i) {
            float a2 = b2;
#pragma unroll 4
            for (int k = 0; k < H2 / 4; ++k) {
                float4 w = w2[k];
                a2 = fmaf(w.x, h1v[i][4 * k + 0], a2);
                a2 = fmaf(w.y, h1v[i][4 * k + 1], a2);
                a2 = fmaf(w.z, h1v[i][4 * k + 2], a2);
                a2 = fmaf(w.w, h1v[i][4 * k + 3], a2);
            }
            out[(size_t)(t0 + i) * NCLS + tid] = a2;
        }
    }
}

extern "C" void kernel_launch(void* const* d_in, const int* in_sizes, int n_in,
                              void* d_out, int out_size, void* d_ws, size_t ws_size,
                              hipStream_t stream) {
    const int* diag = (const int*)d_in[0];
    const int* proc = (const int*)d_in[1];
    const float* emb = (const float*)d_in[2];
    const float* W_ih = (const float*)d_in[3];
    const float* W_hh = (const float*)d_in[4];
    const float* b_ih = (const float*)d_in[5];
    const float* b_hh = (const float*)d_in[6];
    const float* W1 = (const float*)d_in[7];
    const float* b1 = (const float*)d_in[8];
    const float* W_out = (const float*)d_in[9];
    const float* b_out = (const float*)d_in[10];
    float* ws = (float*)d_ws;
    float* out = (float*)d_out;

    hipLaunchKernelGGL(init_kernel, dim3(1), dim3(1024), 0, stream, ws);
    hipLaunchKernelGGL(pool_kernel, dim3(T_STEPS), dim3(256), 0, stream, diag, proc, emb, ws);
    hipLaunchKernelGGL(gx_kernel, dim3(T_STEPS / GX_TB, G4H / 256), dim3(256), 0, stream,
                       W_ih, b_ih, b_hh, ws);
    hipLaunchKernelGGL(lstm_kernel, dim3(LSTM_G), dim3(512), 0, stream, W_hh, ws);
    hipLaunchKernelGGL(mlp_kernel, dim3(T_STEPS / MLP_TB), dim3(256), 0, stream,
                       W1, b1, W_out, b_out, ws, out);
}